// Round 17
// baseline (165.396 us; speedup 1.0000x reference)
//
#include <hip/hip_runtime.h>

#define B_ROWS 8192
#define FEAT   256
#define NBLK   512         // snn blocks; 4160 tiles -> 8.125 per block
#define NJTILE 128         // 64-col j-tiles

typedef float f32x4 __attribute__((ext_vector_type(4)));
typedef _Float16 f16x8 __attribute__((ext_vector_type(8)));

typedef const __attribute__((address_space(1))) unsigned int* gas_ptr;
typedef __attribute__((address_space(3))) unsigned int* las_ptr;

__device__ __forceinline__ void gload_lds16(const void* g, void* l) {
  // HW semantics: LDS dest = wave-uniform base + lane*16 (global src per-lane)
  __builtin_amdgcn_global_load_lds((gas_ptr)g, (las_ptr)l, 16, 0, 0);
}

// cumulative tiles before row it (row r owns jt in [2r,128), 128-2r tiles)
__device__ __forceinline__ int Rc(int it) { return it * (129 - it); }

// ---- kernel 1: fp16 convert -> FRAGMENT-NATIVE layout (proven R17/R19),
// row ssq, per-block partials; zeroes the atomic accumulators.
// xh chunk(C,kk) [1024 B]: byte l*16 = lane l's MFMA fragment for 16-row
// group C, k-slice kk  (C = row>>4; within: quad*256 + r15*16 + half*8).
__global__ __launch_bounds__(256) void prep_kernel(
    const float* __restrict__ x, unsigned short* __restrict__ xh,
    float* __restrict__ sq, float* __restrict__ part_s,
    float* __restrict__ part_q, float* __restrict__ col_den,
    float* __restrict__ col_num, float* __restrict__ row_den,
    float* __restrict__ row_num)
{
  int tid = threadIdx.x;
  int l = tid & 63, wid = tid >> 6;
  int row = blockIdx.x * 4 + wid;
  const float4* xv = (const float4*)(x + (size_t)row * FEAT);
  float4 v = xv[l];            // cols 4l .. 4l+3
  ushort4 u;
  u.x = __builtin_bit_cast(unsigned short, (_Float16)v.x);
  u.y = __builtin_bit_cast(unsigned short, (_Float16)v.y);
  u.z = __builtin_bit_cast(unsigned short, (_Float16)v.z);
  u.w = __builtin_bit_cast(unsigned short, (_Float16)v.w);
  // k0 = 4l: kk = l>>3, quad = (l>>1)&3, half-of-16B = l&1
  size_t off = ((size_t)(row >> 4) * 8 + (l >> 3)) * 1024
             + ((l >> 1) & 3) * 256 + (row & 15) * 16 + (l & 1) * 8;
  *(ushort4*)((char*)xh + off) = u;
  if (tid < 4) {
    int r4 = blockIdx.x * 4 + tid;
    col_den[r4] = 0.f; col_num[r4] = 0.f;
    row_den[r4] = 0.f; row_num[r4] = 0.f;
  }
  float ssq  = v.x*v.x + v.y*v.y + v.z*v.z + v.w*v.w;
  float ssum = v.x + v.y + v.z + v.w;
  #pragma unroll
  for (int m = 32; m; m >>= 1) {
    ssq  += __shfl_xor(ssq, m);
    ssum += __shfl_xor(ssum, m);
  }
  if (l == 0) sq[row] = ssq;
  __shared__ float red[8];
  if (l == 0) { red[wid*2] = ssum; red[wid*2+1] = ssq; }
  __syncthreads();
  if (tid == 0) {
    part_s[blockIdx.x] = red[0]+red[2]+red[4]+red[6];
    part_q[blockIdx.x] = red[1]+red[3]+red[5]+red[7];
  }
}

// ---- epilogue: wave tile 32(i) x NCB*16(j). Row sums -> PERSISTENT
// registers (flushed once per run). COL: credit cols (e(i,j)=e(j,i)) via
// quad reduce + atomicAdd. DIAG: band step, mask i==j (pairs are never
// band/far-mixed since pairing is even-offset; see process_run).
template<int NCB, bool DIAG, bool COL>
__device__ __forceinline__ void epilogue(
    const f32x4 (&acc)[2][8], const float* __restrict__ sq,
    const int* __restrict__ y, int j0, int l15, int l,
    int rbase, const float (&sqi)[8], const int (&yiv)[8],
    float (&sden)[8], float (&snum)[8], float nscale2,
    float* __restrict__ col_den, float* __restrict__ col_num)
{
  int jb = j0 + l15;
  float sqj[NCB]; int yj[NCB];
  #pragma unroll
  for (int cb = 0; cb < NCB; ++cb) {
    int j = jb + cb*16;
    sqj[cb] = sq[j];
    yj[cb]  = y[j];
  }
  float cd[NCB], cn[NCB];
  if (COL) {
    #pragma unroll
    for (int cb = 0; cb < NCB; ++cb) { cd[cb] = 0.f; cn[cb] = 0.f; }
  }
  #pragma unroll
  for (int rb = 0; rb < 2; ++rb) {
    #pragma unroll
    for (int r = 0; r < 4; ++r) {
      float si = sqi[rb*4+r];
      int   ig = rbase + rb*16 + r;
      int   yi = yiv[rb*4+r];
      float dacc = 0.f, nacc = 0.f;
      #pragma unroll
      for (int cb = 0; cb < NCB; ++cb) {
        float S  = acc[rb][cb][r];
        float d2 = fmaf(S, -2.0f, si + sqj[cb]);
        d2 = fmaxf(d2, 0.0f);
        float e  = __builtin_amdgcn_exp2f(__builtin_amdgcn_sqrtf(d2) * nscale2);
        bool same = (yi == yj[cb]);
        bool offd = !DIAG || (ig != jb + cb*16);
        dacc += offd ? e : 0.0f;
        nacc += (same && offd) ? e : 0.0f;
        if (COL) {
          cd[cb] += e;
          cn[cb] += same ? e : 0.0f;
        }
      }
      sden[rb*4+r] += dacc;
      snum[rb*4+r] += nacc;
    }
  }
  if (COL) {
    #pragma unroll
    for (int cb = 0; cb < NCB; ++cb) {
      cd[cb] += __shfl_xor(cd[cb], 16);
      cd[cb] += __shfl_xor(cd[cb], 32);
      cn[cb] += __shfl_xor(cn[cb], 16);
      cn[cb] += __shfl_xor(cn[cb], 32);
    }
    if (l < 16) {
      #pragma unroll
      for (int cb = 0; cb < NCB; ++cb) {
        atomicAdd(&col_den[j0 + cb*16 + l], cd[cb]);
        atomicAdd(&col_num[j0 + cb*16 + l], cn[cb]);
      }
    }
  }
}

__device__ __forceinline__ void do_epilogue(
    bool ppair, bool pdiag, const f32x4 (&acc)[2][8],
    const float* __restrict__ sq, const int* __restrict__ y,
    int j0, int l15, int l, int rbase,
    const float (&sqi)[8], const int (&yiv)[8],
    float (&sden)[8], float (&snum)[8], float nscale2,
    float* __restrict__ col_den, float* __restrict__ col_num)
{
  if (ppair) {
    if (pdiag)
      epilogue<8, true , false>(acc, sq, y, j0, l15, l, rbase, sqi, yiv,
                                sden, snum, nscale2, col_den, col_num);
    else
      epilogue<8, false, true >(acc, sq, y, j0, l15, l, rbase, sqi, yiv,
                                sden, snum, nscale2, col_den, col_num);
  } else {
    if (pdiag)
      epilogue<4, true , false>(acc, sq, y, j0, l15, l, rbase, sqi, yiv,
                                sden, snum, nscale2, col_den, col_num);
    else
      epilogue<4, false, true >(acc, sq, y, j0, l15, l, rbase, sqi, yiv,
                                sden, snum, nscale2, col_den, col_num);
  }
}

// ---- one pipelined run (R25 = R20 schedule + PAIRED 128-col steps):
// row-block `it`, contiguous j-tiles [jt0, jt0+nt). Even-offset consecutive
// tile pairs are processed as ONE step: stage 64 KB once, one barrier pair,
// one epilogue over 8 cb, 128 MFMA per drain (2x work per fixed cost).
// Segment edges degrade to 64-col singles (<=2 per block), so tile-level
// balance (8-9/block, 1.11x makespan) is preserved. Pairs are never
// band/far-mixed: pair {2it+2m, 2it+2m+1} is band iff m==0.
__device__ void process_run(
    int it, int jt0, int nt, const char* __restrict__ xb,
    const float* __restrict__ sq, const int* __restrict__ y,
    float nscale2, int l, int wid, int quad, int l15,
    float* __restrict__ row_den, float* __restrict__ row_num,
    float* __restrict__ col_den, float* __restrict__ col_num,
    char* lB)
{
  // A fragments: chunk C = it*8 + wid*2 + rb, slice kk, byte l*16
  f16x8 areg[2][8];
  #pragma unroll
  for (int rb = 0; rb < 2; ++rb)
    #pragma unroll
    for (int kk = 0; kk < 8; ++kk)
      areg[rb][kk] = *(const f16x8*)(xb +
          ((size_t)(it*8 + wid*2 + rb) * 8 + kk) * 1024 + l*16);

  // per-lane row stats (persistent for the run)
  float sqi[8]; int yiv[8];
  int rbase = it*128 + wid*32 + quad*4;
  #pragma unroll
  for (int rb = 0; rb < 2; ++rb)
    #pragma unroll
    for (int r = 0; r < 4; ++r) {
      int idx = rbase + rb*16 + r;
      sqi[rb*4+r] = sq[idx];
      yiv[rb*4+r] = y[idx];
    }

  float sden[8], snum[8];
  #pragma unroll
  for (int v = 0; v < 8; ++v) { sden[v] = 0.f; snum[v] = 0.f; }
  f32x4 acc[2][8];
  const f32x4 zero4 = {0.f, 0.f, 0.f, 0.f};

  int pjt = -1; bool ppair = false, pdiag = false;
  int m = 0;
  while (m < nt) {
    int jt = jt0 + m;
    bool pair = ((((jt - 2*it) & 1) == 0) && (m + 1 < nt));

    __syncthreads();   // all waves done reading lB (previous step / run)
    // stage: pair = 64 KB (two consecutive panels), single = 32 KB; the
    // fragment-native layout makes both LINEAR from xb + jt*32768.
    {
      const char* gB = xb + (size_t)jt * 32768;
      if (pair) {
        #pragma unroll
        for (int s = 0; s < 16; ++s) {
          int cc = wid*16 + s;
          gload_lds16(gB + cc*1024 + l*16, lB + cc*1024);
        }
      } else {
        #pragma unroll
        for (int s = 0; s < 8; ++s) {
          int cc = wid*8 + s;
          gload_lds16(gB + cc*1024 + l*16, lB + cc*1024);
        }
      }
    }

    if (pjt >= 0)
      do_epilogue(ppair, pdiag, acc, sq, y, pjt*64, l15, l, rbase,
                  sqi, yiv, sden, snum, nscale2, col_den, col_num);
    #pragma unroll
    for (int rb = 0; rb < 2; ++rb)
      #pragma unroll
      for (int cb = 0; cb < 8; ++cb)
        acc[rb][cb] = zero4;

    __syncthreads();   // drains vmcnt: staged panel visible

    if (pair) {
      #pragma unroll
      for (int kk = 0; kk < 8; ++kk) {
        f16x8 bv[8];
        #pragma unroll
        for (int cb = 0; cb < 8; ++cb)
          bv[cb] = *(const f16x8*)(lB + (cb*8 + kk)*1024 + l*16);
        #pragma unroll
        for (int rb = 0; rb < 2; ++rb)
          #pragma unroll
          for (int cb = 0; cb < 8; ++cb)
            acc[rb][cb] = __builtin_amdgcn_mfma_f32_16x16x32_f16(areg[rb][kk], bv[cb], acc[rb][cb], 0, 0, 0);
      }
    } else {
      #pragma unroll
      for (int kk = 0; kk < 8; ++kk) {
        f16x8 bv[4];
        #pragma unroll
        for (int cb = 0; cb < 4; ++cb)
          bv[cb] = *(const f16x8*)(lB + (cb*8 + kk)*1024 + l*16);
        #pragma unroll
        for (int rb = 0; rb < 2; ++rb)
          #pragma unroll
          for (int cb = 0; cb < 4; ++cb)
            acc[rb][cb] = __builtin_amdgcn_mfma_f32_16x16x32_f16(areg[rb][kk], bv[cb], acc[rb][cb], 0, 0, 0);
      }
    }

    pdiag = pair ? (jt == 2*it) : ((jt >> 1) == it);
    pjt = jt; ppair = pair;
    m += pair ? 2 : 1;
  }
  do_epilogue(ppair, pdiag, acc, sq, y, pjt*64, l15, l, rbase,
              sqi, yiv, sden, snum, nscale2, col_den, col_num);

  // flush row sums: quad reduce + atomicAdd (rows shared across blocks)
  #pragma unroll
  for (int v = 0; v < 8; ++v) {
    #pragma unroll
    for (int m2 = 1; m2 <= 8; m2 <<= 1) {
      sden[v] += __shfl_xor(sden[v], m2);
      snum[v] += __shfl_xor(snum[v], m2);
    }
  }
  if (l15 == 0) {
    #pragma unroll
    for (int rb = 0; rb < 2; ++rb)
      #pragma unroll
      for (int r = 0; r < 4; ++r) {
        int ig = rbase + rb*16 + r;
        atomicAdd(&row_den[ig], sden[rb*4+r]);
        atomicAdd(&row_num[ig], snum[rb*4+r]);
      }
  }
}

// ---- kernel 2 (R25): 4160 triangular tiles (it <= jt>>1) flattened
// IT-MAJOR; block b owns [b*65>>3, (b+1)*65>>3) = 8-9 contiguous tiles.
// R23 lesson (final): double-buffering refuted twice -- 2nd barrier was
// never the stall, and the x2-unrolled body spilled (WRITE 39.6 MB).
// This round amortizes per-step fixed costs instead (paired 128-col steps).
__global__ __launch_bounds__(256, 2) void snn_main(
    const unsigned short* __restrict__ xh, const float* __restrict__ sq,
    const int* __restrict__ y, const float* __restrict__ T,
    const float* __restrict__ part_s, const float* __restrict__ part_q,
    float* __restrict__ row_den, float* __restrict__ row_num,
    float* __restrict__ col_den, float* __restrict__ col_num)
{
  __shared__ __align__(16) char lB[65536];
  int tid = threadIdx.x;
  int l = tid & 63, wid = tid >> 6;     // wid = wave row strip (0..3)
  int quad = l >> 4, l15 = l & 15;
  int b = blockIdx.x;
  const char* xb = (const char*)xh;

  // scale from prep's 2048 partials (per-wave redundant; no barrier)
  float s_acc = 0.f, q_acc = 0.f;
  #pragma unroll
  for (int t = 0; t < 32; ++t) {
    s_acc += part_s[l + 64*t];
    q_acc += part_q[l + 64*t];
  }
  #pragma unroll
  for (int m = 1; m <= 32; m <<= 1) {
    s_acc += __shfl_xor(s_acc, m);
    q_acc += __shfl_xor(q_acc, m);
  }
  const double n = (double)B_ROWS * FEAT;
  double var = ((double)q_acc - (double)s_acc*(double)s_acc/n) / (n - 1.0);
  float stdv = (float)sqrt(var);
  float p10  = __builtin_amdgcn_exp2f(T[0] * 3.3219280948873623f);
  float nscale2 = -(p10 * 1.4426950408889634f / stdv);

  // segment [k, kend) of the it-major tile list; decode k -> (it, jt)
  int k    = (b * 65) >> 3;
  int kend = ((b + 1) * 65) >> 3;
  int it = (int)((129.0f - __builtin_amdgcn_sqrtf(16641.0f - 4.0f*(float)k)) * 0.5f);
  if (it < 0) it = 0;
  if (it > 63) it = 63;
  while (it < 63 && Rc(it + 1) <= k) ++it;
  while (it > 0 && Rc(it) > k) --it;

  while (k < kend) {
    int jt0  = 2*it + (k - Rc(it));
    int rowe = Rc(it + 1);                 // first k of next row
    int stop = (kend < rowe) ? kend : rowe;
    int nt   = stop - k;                   // contiguous tiles in this run
    process_run(it, jt0, nt, xb, sq, y, nscale2, l, wid, quad, l15,
                row_den, row_num, col_den, col_num, lB);
    k = stop;
    ++it;
  }
}

// ---- kernel 3: single 1024-thread block; reads only 4 x 32 KB.
// __builtin_amdgcn_logf is LOG2 -> scale by ln(2)  (R4/5/7/9 bug).
__global__ __launch_bounds__(1024) void final_kernel(
    const float* __restrict__ row_den, const float* __restrict__ row_num,
    const float* __restrict__ col_den, const float* __restrict__ col_num,
    float* __restrict__ out)
{
  int tid = threadIdx.x;
  float tot = 0.f;
  #pragma unroll
  for (int rr = 0; rr < 8; ++rr) {
    int row = tid + 1024*rr;
    float den = row_den[row] + col_den[row];
    float num = row_num[row] + col_num[row];
    if (num > 0.f)
      tot += 0.6931471805599453f *
             (__builtin_amdgcn_logf(num) - __builtin_amdgcn_logf(den));
  }
  #pragma unroll
  for (int m = 32; m; m >>= 1) tot += __shfl_xor(tot, m);
  __shared__ float red[16];
  if ((tid & 63) == 0) red[tid >> 6] = tot;
  __syncthreads();
  if (tid == 0) {
    float s = 0.f;
    #pragma unroll
    for (int w = 0; w < 16; ++w) s += red[w];
    out[0] = -s / 8192.0f;
  }
}

extern "C" void kernel_launch(void* const* d_in, const int* in_sizes, int n_in,
                              void* d_out, int out_size, void* d_ws, size_t ws_size,
                              hipStream_t stream)
{
  (void)in_sizes; (void)n_in; (void)out_size; (void)ws_size;
  const float* x  = (const float*)d_in[0];
  const int* y    = (const int*)d_in[1];   // int64 in reference -> int32 here (jax x64 off)
  const float* T  = (const float*)d_in[2];
  char* ws = (char*)d_ws;
  float* part_s = (float*)(ws + 1024);                   // 8 KB
  float* part_q = (float*)(ws + 1024 + 8192);            // 8 KB
  float* sq     = (float*)(ws + 32768);                  // 32 KB
  unsigned short* xh = (unsigned short*)(ws + 65536);    // 4 MB fp16 (fragment layout)
  float* col_den = (float*)(ws + 65536 + 4194304);       // 32 KB
  float* col_num = col_den + B_ROWS;                     // 32 KB
  float* row_den = col_num + B_ROWS;                     // 32 KB
  float* row_num = row_den + B_ROWS;                     // 32 KB

  hipLaunchKernelGGL(prep_kernel, dim3(B_ROWS/4), dim3(256), 0, stream,
                     x, xh, sq, part_s, part_q, col_den, col_num,
                     row_den, row_num);
  hipLaunchKernelGGL(snn_main, dim3(NBLK), dim3(256), 0, stream,
                     xh, sq, y, T, part_s, part_q, row_den, row_num,
                     col_den, col_num);
  hipLaunchKernelGGL(final_kernel, dim3(1), dim3(1024), 0, stream,
                     row_den, row_num, col_den, col_num, (float*)d_out);
}

// Round 18
// 122.256 us; speedup vs baseline: 1.3529x; 1.3529x over previous
//
#include <hip/hip_runtime.h>

#define B_ROWS 8192
#define FEAT   256
#define NBLK   512         // snn blocks; 4160 tiles -> 8.125 per block
#define NJTILE 128         // 64-col j-tiles

typedef float f32x4 __attribute__((ext_vector_type(4)));
typedef _Float16 f16x8 __attribute__((ext_vector_type(8)));

typedef const __attribute__((address_space(1))) unsigned int* gas_ptr;
typedef __attribute__((address_space(3))) unsigned int* las_ptr;

__device__ __forceinline__ void gload_lds16(const void* g, void* l) {
  // HW semantics: LDS dest = wave-uniform base + lane*16 (global src per-lane)
  __builtin_amdgcn_global_load_lds((gas_ptr)g, (las_ptr)l, 16, 0, 0);
}

// cumulative tiles before row it (row r owns jt in [2r,128), 128-2r tiles)
__device__ __forceinline__ int Rc(int it) { return it * (129 - it); }

// ---- kernel 1: fp16 convert -> FRAGMENT-NATIVE layout (proven R17/R19),
// row ssq, per-block partials; zeroes the atomic accumulators.
// xh chunk(C,kk) [1024 B]: byte l*16 = lane l's MFMA fragment for 16-row
// group C, k-slice kk  (C = row>>4; within: quad*256 + r15*16 + half*8).
__global__ __launch_bounds__(256) void prep_kernel(
    const float* __restrict__ x, unsigned short* __restrict__ xh,
    float* __restrict__ sq, float* __restrict__ part_s,
    float* __restrict__ part_q, float* __restrict__ col_den,
    float* __restrict__ col_num, float* __restrict__ row_den,
    float* __restrict__ row_num)
{
  int tid = threadIdx.x;
  int l = tid & 63, wid = tid >> 6;
  int row = blockIdx.x * 4 + wid;
  const float4* xv = (const float4*)(x + (size_t)row * FEAT);
  float4 v = xv[l];            // cols 4l .. 4l+3
  ushort4 u;
  u.x = __builtin_bit_cast(unsigned short, (_Float16)v.x);
  u.y = __builtin_bit_cast(unsigned short, (_Float16)v.y);
  u.z = __builtin_bit_cast(unsigned short, (_Float16)v.z);
  u.w = __builtin_bit_cast(unsigned short, (_Float16)v.w);
  // k0 = 4l: kk = l>>3, quad = (l>>1)&3, half-of-16B = l&1
  size_t off = ((size_t)(row >> 4) * 8 + (l >> 3)) * 1024
             + ((l >> 1) & 3) * 256 + (row & 15) * 16 + (l & 1) * 8;
  *(ushort4*)((char*)xh + off) = u;
  if (tid < 4) {
    int r4 = blockIdx.x * 4 + tid;
    col_den[r4] = 0.f; col_num[r4] = 0.f;
    row_den[r4] = 0.f; row_num[r4] = 0.f;
  }
  float ssq  = v.x*v.x + v.y*v.y + v.z*v.z + v.w*v.w;
  float ssum = v.x + v.y + v.z + v.w;
  #pragma unroll
  for (int m = 32; m; m >>= 1) {
    ssq  += __shfl_xor(ssq, m);
    ssum += __shfl_xor(ssum, m);
  }
  if (l == 0) sq[row] = ssq;
  __shared__ float red[8];
  if (l == 0) { red[wid*2] = ssum; red[wid*2+1] = ssq; }
  __syncthreads();
  if (tid == 0) {
    part_s[blockIdx.x] = red[0]+red[2]+red[4]+red[6];
    part_q[blockIdx.x] = red[1]+red[3]+red[5]+red[7];
  }
}

// ---- epilogue: wave tile 32(i) x NCB*16(j). Row sums -> PERSISTENT
// registers (flushed once per run). COL: credit cols (e(i,j)=e(j,i)) via
// quad reduce + atomicAdd. DIAG: band step, mask i==j (pairs are never
// band/far-mixed since pairing is even-offset; see process_run).
template<int NCB, bool DIAG, bool COL>
__device__ __forceinline__ void epilogue(
    const f32x4 (&acc)[2][8], const float* __restrict__ sq,
    const int* __restrict__ y, int j0, int l15, int l,
    int rbase, const float (&sqi)[8], const int (&yiv)[8],
    float (&sden)[8], float (&snum)[8], float nscale2,
    float* __restrict__ col_den, float* __restrict__ col_num)
{
  int jb = j0 + l15;
  float sqj[NCB]; int yj[NCB];
  #pragma unroll
  for (int cb = 0; cb < NCB; ++cb) {
    int j = jb + cb*16;
    sqj[cb] = sq[j];
    yj[cb]  = y[j];
  }
  float cd[NCB], cn[NCB];
  if (COL) {
    #pragma unroll
    for (int cb = 0; cb < NCB; ++cb) { cd[cb] = 0.f; cn[cb] = 0.f; }
  }
  #pragma unroll
  for (int rb = 0; rb < 2; ++rb) {
    #pragma unroll
    for (int r = 0; r < 4; ++r) {
      float si = sqi[rb*4+r];
      int   ig = rbase + rb*16 + r;
      int   yi = yiv[rb*4+r];
      float dacc = 0.f, nacc = 0.f;
      #pragma unroll
      for (int cb = 0; cb < NCB; ++cb) {
        float S  = acc[rb][cb][r];
        float d2 = fmaf(S, -2.0f, si + sqj[cb]);
        d2 = fmaxf(d2, 0.0f);
        float e  = __builtin_amdgcn_exp2f(__builtin_amdgcn_sqrtf(d2) * nscale2);
        bool same = (yi == yj[cb]);
        bool offd = !DIAG || (ig != jb + cb*16);
        dacc += offd ? e : 0.0f;
        nacc += (same && offd) ? e : 0.0f;
        if (COL) {
          cd[cb] += e;
          cn[cb] += same ? e : 0.0f;
        }
      }
      sden[rb*4+r] += dacc;
      snum[rb*4+r] += nacc;
    }
  }
  if (COL) {
    #pragma unroll
    for (int cb = 0; cb < NCB; ++cb) {
      cd[cb] += __shfl_xor(cd[cb], 16);
      cd[cb] += __shfl_xor(cd[cb], 32);
      cn[cb] += __shfl_xor(cn[cb], 16);
      cn[cb] += __shfl_xor(cn[cb], 32);
    }
    if (l < 16) {
      #pragma unroll
      for (int cb = 0; cb < NCB; ++cb) {
        atomicAdd(&col_den[j0 + cb*16 + l], cd[cb]);
        atomicAdd(&col_num[j0 + cb*16 + l], cn[cb]);
      }
    }
  }
}

__device__ __forceinline__ void do_epilogue(
    bool ppair, bool pdiag, const f32x4 (&acc)[2][8],
    const float* __restrict__ sq, const int* __restrict__ y,
    int j0, int l15, int l, int rbase,
    const float (&sqi)[8], const int (&yiv)[8],
    float (&sden)[8], float (&snum)[8], float nscale2,
    float* __restrict__ col_den, float* __restrict__ col_num)
{
  if (ppair) {
    if (pdiag)
      epilogue<8, true , false>(acc, sq, y, j0, l15, l, rbase, sqi, yiv,
                                sden, snum, nscale2, col_den, col_num);
    else
      epilogue<8, false, true >(acc, sq, y, j0, l15, l, rbase, sqi, yiv,
                                sden, snum, nscale2, col_den, col_num);
  } else {
    if (pdiag)
      epilogue<4, true , false>(acc, sq, y, j0, l15, l, rbase, sqi, yiv,
                                sden, snum, nscale2, col_den, col_num);
    else
      epilogue<4, false, true >(acc, sq, y, j0, l15, l, rbase, sqi, yiv,
                                sden, snum, nscale2, col_den, col_num);
  }
}

// ---- one pipelined run (R25 schedule + PAIRED 128-col steps): row-block
// `it`, contiguous j-tiles [jt0, jt0+nt). Even-offset consecutive tile
// pairs are ONE step: stage 64 KB once, one barrier pair, one epilogue over
// 8 cb, 128 MFMA per drain (2x work per fixed cost). Segment edges degrade
// to 64-col singles (<=2/block) -> tile-level balance preserved. Pairs are
// never band/far-mixed: pair {2it+2m, 2it+2m+1} is band iff m==0.
__device__ void process_run(
    int it, int jt0, int nt, const char* __restrict__ xb,
    const float* __restrict__ sq, const int* __restrict__ y,
    float nscale2, int l, int wid, int quad, int l15,
    float* __restrict__ row_den, float* __restrict__ row_num,
    float* __restrict__ col_den, float* __restrict__ col_num,
    char* lB)
{
  // A fragments: chunk C = it*8 + wid*2 + rb, slice kk, byte l*16
  f16x8 areg[2][8];
  #pragma unroll
  for (int rb = 0; rb < 2; ++rb)
    #pragma unroll
    for (int kk = 0; kk < 8; ++kk)
      areg[rb][kk] = *(const f16x8*)(xb +
          ((size_t)(it*8 + wid*2 + rb) * 8 + kk) * 1024 + l*16);

  // per-lane row stats (persistent for the run)
  float sqi[8]; int yiv[8];
  int rbase = it*128 + wid*32 + quad*4;
  #pragma unroll
  for (int rb = 0; rb < 2; ++rb)
    #pragma unroll
    for (int r = 0; r < 4; ++r) {
      int idx = rbase + rb*16 + r;
      sqi[rb*4+r] = sq[idx];
      yiv[rb*4+r] = y[idx];
    }

  float sden[8], snum[8];
  #pragma unroll
  for (int v = 0; v < 8; ++v) { sden[v] = 0.f; snum[v] = 0.f; }
  f32x4 acc[2][8];
  const f32x4 zero4 = {0.f, 0.f, 0.f, 0.f};

  int pjt = -1; bool ppair = false, pdiag = false;
  int m = 0;
  while (m < nt) {
    int jt = jt0 + m;
    bool pair = ((((jt - 2*it) & 1) == 0) && (m + 1 < nt));

    __syncthreads();   // all waves done reading lB (previous step / run)
    // stage: pair = 64 KB (two consecutive panels), single = 32 KB; the
    // fragment-native layout makes both LINEAR from xb + jt*32768.
    {
      const char* gB = xb + (size_t)jt * 32768;
      if (pair) {
        #pragma unroll
        for (int s = 0; s < 16; ++s) {
          int cc = wid*16 + s;
          gload_lds16(gB + cc*1024 + l*16, lB + cc*1024);
        }
      } else {
        #pragma unroll
        for (int s = 0; s < 8; ++s) {
          int cc = wid*8 + s;
          gload_lds16(gB + cc*1024 + l*16, lB + cc*1024);
        }
      }
    }

    if (pjt >= 0)
      do_epilogue(ppair, pdiag, acc, sq, y, pjt*64, l15, l, rbase,
                  sqi, yiv, sden, snum, nscale2, col_den, col_num);
    #pragma unroll
    for (int rb = 0; rb < 2; ++rb)
      #pragma unroll
      for (int cb = 0; cb < 8; ++cb)
        acc[rb][cb] = zero4;

    __syncthreads();   // drains vmcnt: staged panel visible

    if (pair) {
      #pragma unroll
      for (int kk = 0; kk < 8; ++kk) {
        f16x8 bv[8];
        #pragma unroll
        for (int cb = 0; cb < 8; ++cb)
          bv[cb] = *(const f16x8*)(lB + (cb*8 + kk)*1024 + l*16);
        #pragma unroll
        for (int rb = 0; rb < 2; ++rb)
          #pragma unroll
          for (int cb = 0; cb < 8; ++cb)
            acc[rb][cb] = __builtin_amdgcn_mfma_f32_16x16x32_f16(areg[rb][kk], bv[cb], acc[rb][cb], 0, 0, 0);
      }
    } else {
      #pragma unroll
      for (int kk = 0; kk < 8; ++kk) {
        f16x8 bv[4];
        #pragma unroll
        for (int cb = 0; cb < 4; ++cb)
          bv[cb] = *(const f16x8*)(lB + (cb*8 + kk)*1024 + l*16);
        #pragma unroll
        for (int rb = 0; rb < 2; ++rb)
          #pragma unroll
          for (int cb = 0; cb < 4; ++cb)
            acc[rb][cb] = __builtin_amdgcn_mfma_f32_16x16x32_f16(areg[rb][kk], bv[cb], acc[rb][cb], 0, 0, 0);
      }
    }

    pdiag = pair ? (jt == 2*it) : ((jt >> 1) == it);
    pjt = jt; ppair = pair;
    m += pair ? 2 : 1;
  }
  do_epilogue(ppair, pdiag, acc, sq, y, pjt*64, l15, l, rbase,
              sqi, yiv, sden, snum, nscale2, col_den, col_num);

  // flush row sums: quad reduce + atomicAdd (rows shared across blocks)
  #pragma unroll
  for (int v = 0; v < 8; ++v) {
    #pragma unroll
    for (int m2 = 1; m2 <= 8; m2 <<= 1) {
      sden[v] += __shfl_xor(sden[v], m2);
      snum[v] += __shfl_xor(snum[v], m2);
    }
  }
  if (l15 == 0) {
    #pragma unroll
    for (int rb = 0; rb < 2; ++rb)
      #pragma unroll
      for (int r = 0; r < 4; ++r) {
        int ig = rbase + rb*16 + r;
        atomicAdd(&row_den[ig], sden[rb*4+r]);
        atomicAdd(&row_num[ig], snum[rb*4+r]);
      }
  }
}

// ---- kernel 2 (R26 = R25 + launch_bounds(256,1)): 4160 triangular tiles
// (it <= jt>>1) flattened IT-MAJOR; block b owns [b*65>>3, (b+1)*65>>3)
// = 8-9 contiguous tiles. R17 post-mortem: launch_bounds(256,N) caps VGPR
// at 256/N -- (256,2)'s 128-cap spilled the paired-acc set (WRITE 204 MB).
// (256,1) -> cap 256; natural demand ~180 fits. Per m69, waves/CU only
// halves at the >256 boundary, so 2 blocks/CU residency is UNCHANGED
// (LDS 2 x 64 KB = 128 <= 160 KB).
__global__ __launch_bounds__(256, 1) void snn_main(
    const unsigned short* __restrict__ xh, const float* __restrict__ sq,
    const int* __restrict__ y, const float* __restrict__ T,
    const float* __restrict__ part_s, const float* __restrict__ part_q,
    float* __restrict__ row_den, float* __restrict__ row_num,
    float* __restrict__ col_den, float* __restrict__ col_num)
{
  __shared__ __align__(16) char lB[65536];
  int tid = threadIdx.x;
  int l = tid & 63, wid = tid >> 6;     // wid = wave row strip (0..3)
  int quad = l >> 4, l15 = l & 15;
  int b = blockIdx.x;
  const char* xb = (const char*)xh;

  // scale from prep's 2048 partials (per-wave redundant; no barrier)
  float s_acc = 0.f, q_acc = 0.f;
  #pragma unroll
  for (int t = 0; t < 32; ++t) {
    s_acc += part_s[l + 64*t];
    q_acc += part_q[l + 64*t];
  }
  #pragma unroll
  for (int m = 1; m <= 32; m <<= 1) {
    s_acc += __shfl_xor(s_acc, m);
    q_acc += __shfl_xor(q_acc, m);
  }
  const double n = (double)B_ROWS * FEAT;
  double var = ((double)q_acc - (double)s_acc*(double)s_acc/n) / (n - 1.0);
  float stdv = (float)sqrt(var);
  float p10  = __builtin_amdgcn_exp2f(T[0] * 3.3219280948873623f);
  float nscale2 = -(p10 * 1.4426950408889634f / stdv);

  // segment [k, kend) of the it-major tile list; decode k -> (it, jt)
  int k    = (b * 65) >> 3;
  int kend = ((b + 1) * 65) >> 3;
  int it = (int)((129.0f - __builtin_amdgcn_sqrtf(16641.0f - 4.0f*(float)k)) * 0.5f);
  if (it < 0) it = 0;
  if (it > 63) it = 63;
  while (it < 63 && Rc(it + 1) <= k) ++it;
  while (it > 0 && Rc(it) > k) --it;

  while (k < kend) {
    int jt0  = 2*it + (k - Rc(it));
    int rowe = Rc(it + 1);                 // first k of next row
    int stop = (kend < rowe) ? kend : rowe;
    int nt   = stop - k;                   // contiguous tiles in this run
    process_run(it, jt0, nt, xb, sq, y, nscale2, l, wid, quad, l15,
                row_den, row_num, col_den, col_num, lB);
    k = stop;
    ++it;
  }
}

// ---- kernel 3: single 1024-thread block; reads only 4 x 32 KB.
// __builtin_amdgcn_logf is LOG2 -> scale by ln(2)  (R4/5/7/9 bug).
__global__ __launch_bounds__(1024) void final_kernel(
    const float* __restrict__ row_den, const float* __restrict__ row_num,
    const float* __restrict__ col_den, const float* __restrict__ col_num,
    float* __restrict__ out)
{
  int tid = threadIdx.x;
  float tot = 0.f;
  #pragma unroll
  for (int rr = 0; rr < 8; ++rr) {
    int row = tid + 1024*rr;
    float den = row_den[row] + col_den[row];
    float num = row_num[row] + col_num[row];
    if (num > 0.f)
      tot += 0.6931471805599453f *
             (__builtin_amdgcn_logf(num) - __builtin_amdgcn_logf(den));
  }
  #pragma unroll
  for (int m = 32; m; m >>= 1) tot += __shfl_xor(tot, m);
  __shared__ float red[16];
  if ((tid & 63) == 0) red[tid >> 6] = tot;
  __syncthreads();
  if (tid == 0) {
    float s = 0.f;
    #pragma unroll
    for (int w = 0; w < 16; ++w) s += red[w];
    out[0] = -s / 8192.0f;
  }
}

extern "C" void kernel_launch(void* const* d_in, const int* in_sizes, int n_in,
                              void* d_out, int out_size, void* d_ws, size_t ws_size,
                              hipStream_t stream)
{
  (void)in_sizes; (void)n_in; (void)out_size; (void)ws_size;
  const float* x  = (const float*)d_in[0];
  const int* y    = (const int*)d_in[1];   // int64 in reference -> int32 here (jax x64 off)
  const float* T  = (const float*)d_in[2];
  char* ws = (char*)d_ws;
  float* part_s = (float*)(ws + 1024);                   // 8 KB
  float* part_q = (float*)(ws + 1024 + 8192);            // 8 KB
  float* sq     = (float*)(ws + 32768);                  // 32 KB
  unsigned short* xh = (unsigned short*)(ws + 65536);    // 4 MB fp16 (fragment layout)
  float* col_den = (float*)(ws + 65536 + 4194304);       // 32 KB
  float* col_num = col_den + B_ROWS;                     // 32 KB
  float* row_den = col_num + B_ROWS;                     // 32 KB
  float* row_num = row_den + B_ROWS;                     // 32 KB

  hipLaunchKernelGGL(prep_kernel, dim3(B_ROWS/4), dim3(256), 0, stream,
                     x, xh, sq, part_s, part_q, col_den, col_num,
                     row_den, row_num);
  hipLaunchKernelGGL(snn_main, dim3(NBLK), dim3(256), 0, stream,
                     xh, sq, y, T, part_s, part_q, row_den, row_num,
                     col_den, col_num);
  hipLaunchKernelGGL(final_kernel, dim3(1), dim3(1024), 0, stream,
                     row_den, row_num, col_den, col_num, (float*)d_out);
}

// Round 19
// 105.160 us; speedup vs baseline: 1.5728x; 1.1626x over previous
//
#include <hip/hip_runtime.h>

#define B_ROWS 8192
#define FEAT   256
#define NBLK   512         // snn blocks; 4160 tiles -> 8.125 per block
#define NJTILE 128         // 64-col j-tiles

typedef float f32x4 __attribute__((ext_vector_type(4)));
typedef _Float16 f16x8 __attribute__((ext_vector_type(8)));

typedef const __attribute__((address_space(1))) unsigned int* gas_ptr;
typedef __attribute__((address_space(3))) unsigned int* las_ptr;

__device__ __forceinline__ void gload_lds16(const void* g, void* l) {
  // HW semantics: LDS dest = wave-uniform base + lane*16 (global src per-lane)
  __builtin_amdgcn_global_load_lds((gas_ptr)g, (las_ptr)l, 16, 0, 0);
}

// cumulative tiles before row it (row r owns jt in [2r,128), 128-2r tiles)
__device__ __forceinline__ int Rc(int it) { return it * (129 - it); }

// ---- kernel 1: fp16 convert -> FRAGMENT-NATIVE layout (proven R17/R19),
// row ssq, per-block partials; zeroes the atomic accumulators.
// xh chunk(C,kk) [1024 B]: byte l*16 = lane l's MFMA fragment for 16-row
// group C, k-slice kk  (C = row>>4; within: quad*256 + r15*16 + half*8).
__global__ __launch_bounds__(256) void prep_kernel(
    const float* __restrict__ x, unsigned short* __restrict__ xh,
    float* __restrict__ sq, float* __restrict__ part_s,
    float* __restrict__ part_q, float* __restrict__ col_den,
    float* __restrict__ col_num, float* __restrict__ row_den,
    float* __restrict__ row_num)
{
  int tid = threadIdx.x;
  int l = tid & 63, wid = tid >> 6;
  int row = blockIdx.x * 4 + wid;
  const float4* xv = (const float4*)(x + (size_t)row * FEAT);
  float4 v = xv[l];            // cols 4l .. 4l+3
  ushort4 u;
  u.x = __builtin_bit_cast(unsigned short, (_Float16)v.x);
  u.y = __builtin_bit_cast(unsigned short, (_Float16)v.y);
  u.z = __builtin_bit_cast(unsigned short, (_Float16)v.z);
  u.w = __builtin_bit_cast(unsigned short, (_Float16)v.w);
  // k0 = 4l: kk = l>>3, quad = (l>>1)&3, half-of-16B = l&1
  size_t off = ((size_t)(row >> 4) * 8 + (l >> 3)) * 1024
             + ((l >> 1) & 3) * 256 + (row & 15) * 16 + (l & 1) * 8;
  *(ushort4*)((char*)xh + off) = u;
  if (tid < 4) {
    int r4 = blockIdx.x * 4 + tid;
    col_den[r4] = 0.f; col_num[r4] = 0.f;
    row_den[r4] = 0.f; row_num[r4] = 0.f;
  }
  float ssq  = v.x*v.x + v.y*v.y + v.z*v.z + v.w*v.w;
  float ssum = v.x + v.y + v.z + v.w;
  #pragma unroll
  for (int m = 32; m; m >>= 1) {
    ssq  += __shfl_xor(ssq, m);
    ssum += __shfl_xor(ssum, m);
  }
  if (l == 0) sq[row] = ssq;
  __shared__ float red[8];
  if (l == 0) { red[wid*2] = ssum; red[wid*2+1] = ssq; }
  __syncthreads();
  if (tid == 0) {
    part_s[blockIdx.x] = red[0]+red[2]+red[4]+red[6];
    part_q[blockIdx.x] = red[1]+red[3]+red[5]+red[7];
  }
}

// ---- epilogue: wave tile 32(i) x 64(j). Row sums -> PERSISTENT registers
// (flushed once per run -- R10's cheap path). Far tiles also credit cols
// (e(i,j)=e(j,i)): per-tile quad reduce + atomicAdd (proven R15 path).
// DIAG: band tile (jt>>1 == it), mask i==j, rows only.
template<bool DIAG>
__device__ __forceinline__ void epilogue(
    const f32x4 (&acc)[2][4], const float* __restrict__ sq,
    const int* __restrict__ y, int j0, int l15, int l,
    int rbase, const float (&sqi)[8], const int (&yiv)[8],
    float (&sden)[8], float (&snum)[8], float nscale2,
    float* __restrict__ col_den, float* __restrict__ col_num)
{
  int jb = j0 + l15;
  float sqj[4]; int yj[4];
  #pragma unroll
  for (int cb = 0; cb < 4; ++cb) {
    int j = jb + cb*16;
    sqj[cb] = sq[j];
    yj[cb]  = y[j];
  }
  float cd[4], cn[4];
  if (!DIAG) {
    #pragma unroll
    for (int cb = 0; cb < 4; ++cb) { cd[cb] = 0.f; cn[cb] = 0.f; }
  }
  #pragma unroll
  for (int rb = 0; rb < 2; ++rb) {
    #pragma unroll
    for (int r = 0; r < 4; ++r) {
      float si = sqi[rb*4+r];
      int   ig = rbase + rb*16 + r;
      int   yi = yiv[rb*4+r];
      float dacc = 0.f, nacc = 0.f;
      #pragma unroll
      for (int cb = 0; cb < 4; ++cb) {
        float S  = acc[rb][cb][r];
        float d2 = fmaf(S, -2.0f, si + sqj[cb]);
        d2 = fmaxf(d2, 0.0f);
        float e  = __builtin_amdgcn_exp2f(__builtin_amdgcn_sqrtf(d2) * nscale2);
        bool same = (yi == yj[cb]);
        bool offd = !DIAG || (ig != jb + cb*16);
        dacc += offd ? e : 0.0f;
        nacc += (same && offd) ? e : 0.0f;
        if (!DIAG) {
          cd[cb] += e;
          cn[cb] += same ? e : 0.0f;
        }
      }
      sden[rb*4+r] += dacc;
      snum[rb*4+r] += nacc;
    }
  }
  if (!DIAG) {
    #pragma unroll
    for (int cb = 0; cb < 4; ++cb) {
      cd[cb] += __shfl_xor(cd[cb], 16);
      cd[cb] += __shfl_xor(cd[cb], 32);
      cn[cb] += __shfl_xor(cn[cb], 16);
      cn[cb] += __shfl_xor(cn[cb], 32);
    }
    if (l < 16) {
      #pragma unroll
      for (int cb = 0; cb < 4; ++cb) {
        atomicAdd(&col_den[j0 + cb*16 + l], cd[cb]);
        atomicAdd(&col_num[j0 + cb*16 + l], cn[cb]);
      }
    }
  }
}

// ---- one pipelined run: row-block `it`, contiguous j-tiles [jt0, jt0+nt).
// R10's proven 2-barrier structure: stage(jt) || epilogue(jt-1) || MFMA(jt).
// areg loaded once; row sums persist in registers, flushed at run end.
__device__ __forceinline__ void process_run(
    int it, int jt0, int nt, const char* __restrict__ xb,
    const float* __restrict__ sq, const int* __restrict__ y,
    float nscale2, int l, int wid, int quad, int l15,
    float* __restrict__ row_den, float* __restrict__ row_num,
    float* __restrict__ col_den, float* __restrict__ col_num,
    char* lB)
{
  // A fragments: chunk C = it*8 + wid*2 + rb, slice kk, byte l*16
  f16x8 areg[2][8];
  #pragma unroll
  for (int rb = 0; rb < 2; ++rb)
    #pragma unroll
    for (int kk = 0; kk < 8; ++kk)
      areg[rb][kk] = *(const f16x8*)(xb +
          ((size_t)(it*8 + wid*2 + rb) * 8 + kk) * 1024 + l*16);

  // per-lane row stats (persistent for the run)
  float sqi[8]; int yiv[8];
  int rbase = it*128 + wid*32 + quad*4;
  #pragma unroll
  for (int rb = 0; rb < 2; ++rb)
    #pragma unroll
    for (int r = 0; r < 4; ++r) {
      int idx = rbase + rb*16 + r;
      sqi[rb*4+r] = sq[idx];
      yiv[rb*4+r] = y[idx];
    }

  float sden[8], snum[8];
  #pragma unroll
  for (int v = 0; v < 8; ++v) { sden[v] = 0.f; snum[v] = 0.f; }
  f32x4 acc[2][4];
  const f32x4 zero4 = {0.f, 0.f, 0.f, 0.f};

  for (int n = 0; n < nt; ++n) {
    int jt = jt0 + n;

    __syncthreads();   // all waves done reading lB (previous tile / run)
    // stage B panel jt: 32 KB linear (fragment-native src == LDS layout)
    {
      const char* gB = xb + (size_t)jt * 32768;
      #pragma unroll
      for (int s = 0; s < 8; ++s) {
        int cc = wid*8 + s;
        gload_lds16(gB + cc*1024 + l*16, lB + cc*1024);
      }
    }

    if (n > 0) {
      int pjt = jt - 1;
      if ((pjt >> 1) == it)
        epilogue<true >(acc, sq, y, pjt*64, l15, l, rbase, sqi, yiv,
                        sden, snum, nscale2, col_den, col_num);
      else
        epilogue<false>(acc, sq, y, pjt*64, l15, l, rbase, sqi, yiv,
                        sden, snum, nscale2, col_den, col_num);
    }
    #pragma unroll
    for (int rb = 0; rb < 2; ++rb)
      #pragma unroll
      for (int cb = 0; cb < 4; ++cb)
        acc[rb][cb] = zero4;

    __syncthreads();   // drains vmcnt: B panel visible

    #pragma unroll
    for (int kk = 0; kk < 8; ++kk) {
      f16x8 bv[4];
      #pragma unroll
      for (int cb = 0; cb < 4; ++cb)
        bv[cb] = *(const f16x8*)(lB + (cb*8 + kk)*1024 + l*16);
      #pragma unroll
      for (int rb = 0; rb < 2; ++rb)
        #pragma unroll
        for (int cb = 0; cb < 4; ++cb)
          acc[rb][cb] = __builtin_amdgcn_mfma_f32_16x16x32_f16(areg[rb][kk], bv[cb], acc[rb][cb], 0, 0, 0);
    }
  }
  {
    int pjt = jt0 + nt - 1;
    if ((pjt >> 1) == it)
      epilogue<true >(acc, sq, y, pjt*64, l15, l, rbase, sqi, yiv,
                      sden, snum, nscale2, col_den, col_num);
    else
      epilogue<false>(acc, sq, y, pjt*64, l15, l, rbase, sqi, yiv,
                      sden, snum, nscale2, col_den, col_num);
  }

  // flush row sums: quad reduce + atomicAdd (rows shared across blocks)
  #pragma unroll
  for (int v = 0; v < 8; ++v) {
    #pragma unroll
    for (int m = 1; m <= 8; m <<= 1) {
      sden[v] += __shfl_xor(sden[v], m);
      snum[v] += __shfl_xor(snum[v], m);
    }
  }
  if (l15 == 0) {
    #pragma unroll
    for (int rb = 0; rb < 2; ++rb)
      #pragma unroll
      for (int r = 0; r < 4; ++r) {
        int ig = rbase + rb*16 + r;
        atomicAdd(&row_den[ig], sden[rb*4+r]);
        atomicAdd(&row_num[ig], snum[rb*4+r]);
      }
  }
}

// ---- kernel 2 (R20, the measured session optimum: 50.6us / 107.5us total):
// 4160 triangular tiles (it <= jt>>1; 128-row x 64-col) flattened IT-MAJOR;
// block b owns [b*65>>3, (b+1)*65>>3) = 8-9 contiguous tiles; 7/8 of blocks
// get a SINGLE run -> one areg load, full-depth pipeline (stage ||
// epilogue(prev) || MFMA). Session-final lessons, all counter-evidenced:
//  - VGPR 128 is the sharp optimum: >128 halves waves/SIMD (R18: 200 VGPR,
//    occ 16.9->9.1%, 61us); launch_bounds caps <128 spill (R1/R7/R17).
//  - 2nd-barrier/staging drain is NOT the stall (dbuf refuted R2/R16).
//  - Fusion phase-aligns co-resident blocks -> 2x stall (R14); the ~53us
//    outside the kernels is harness-fixed (single-dispatch measurement).
//  - LDS-free B is L2-latency-bound (R8); panel-residency is neutral (R9).
__global__ __launch_bounds__(256, 2) void snn_main(
    const unsigned short* __restrict__ xh, const float* __restrict__ sq,
    const int* __restrict__ y, const float* __restrict__ T,
    const float* __restrict__ part_s, const float* __restrict__ part_q,
    float* __restrict__ row_den, float* __restrict__ row_num,
    float* __restrict__ col_den, float* __restrict__ col_num)
{
  __shared__ __align__(16) char lB[32768];
  int tid = threadIdx.x;
  int l = tid & 63, wid = tid >> 6;     // wid = wave row strip (0..3)
  int quad = l >> 4, l15 = l & 15;
  int b = blockIdx.x;
  const char* xb = (const char*)xh;

  // scale from prep's 2048 partials (per-wave redundant; no barrier)
  float s_acc = 0.f, q_acc = 0.f;
  #pragma unroll
  for (int t = 0; t < 32; ++t) {
    s_acc += part_s[l + 64*t];
    q_acc += part_q[l + 64*t];
  }
  #pragma unroll
  for (int m = 1; m <= 32; m <<= 1) {
    s_acc += __shfl_xor(s_acc, m);
    q_acc += __shfl_xor(q_acc, m);
  }
  const double n = (double)B_ROWS * FEAT;
  double var = ((double)q_acc - (double)s_acc*(double)s_acc/n) / (n - 1.0);
  float stdv = (float)sqrt(var);
  float p10  = __builtin_amdgcn_exp2f(T[0] * 3.3219280948873623f);
  float nscale2 = -(p10 * 1.4426950408889634f / stdv);

  // segment [k, kend) of the it-major tile list; decode k -> (it, jt)
  int k    = (b * 65) >> 3;
  int kend = ((b + 1) * 65) >> 3;
  int it = (int)((129.0f - __builtin_amdgcn_sqrtf(16641.0f - 4.0f*(float)k)) * 0.5f);
  if (it < 0) it = 0;
  if (it > 63) it = 63;
  while (it < 63 && Rc(it + 1) <= k) ++it;
  while (it > 0 && Rc(it) > k) --it;

  while (k < kend) {
    int jt0  = 2*it + (k - Rc(it));
    int rowe = Rc(it + 1);                 // first k of next row
    int stop = (kend < rowe) ? kend : rowe;
    int nt   = stop - k;                   // contiguous tiles in this run
    process_run(it, jt0, nt, xb, sq, y, nscale2, l, wid, quad, l15,
                row_den, row_num, col_den, col_num, lB);
    k = stop;
    ++it;
  }
}

// ---- kernel 3: single 1024-thread block; reads only 4 x 32 KB.
// __builtin_amdgcn_logf is LOG2 -> scale by ln(2)  (R4/5/7/9 bug).
__global__ __launch_bounds__(1024) void final_kernel(
    const float* __restrict__ row_den, const float* __restrict__ row_num,
    const float* __restrict__ col_den, const float* __restrict__ col_num,
    float* __restrict__ out)
{
  int tid = threadIdx.x;
  float tot = 0.f;
  #pragma unroll
  for (int rr = 0; rr < 8; ++rr) {
    int row = tid + 1024*rr;
    float den = row_den[row] + col_den[row];
    float num = row_num[row] + col_num[row];
    if (num > 0.f)
      tot += 0.6931471805599453f *
             (__builtin_amdgcn_logf(num) - __builtin_amdgcn_logf(den));
  }
  #pragma unroll
  for (int m = 32; m; m >>= 1) tot += __shfl_xor(tot, m);
  __shared__ float red[16];
  if ((tid & 63) == 0) red[tid >> 6] = tot;
  __syncthreads();
  if (tid == 0) {
    float s = 0.f;
    #pragma unroll
    for (int w = 0; w < 16; ++w) s += red[w];
    out[0] = -s / 8192.0f;
  }
}

extern "C" void kernel_launch(void* const* d_in, const int* in_sizes, int n_in,
                              void* d_out, int out_size, void* d_ws, size_t ws_size,
                              hipStream_t stream)
{
  (void)in_sizes; (void)n_in; (void)out_size; (void)ws_size;
  const float* x  = (const float*)d_in[0];
  const int* y    = (const int*)d_in[1];   // int64 in reference -> int32 here (jax x64 off)
  const float* T  = (const float*)d_in[2];
  char* ws = (char*)d_ws;
  float* part_s = (float*)(ws + 1024);                   // 8 KB
  float* part_q = (float*)(ws + 1024 + 8192);            // 8 KB
  float* sq     = (float*)(ws + 32768);                  // 32 KB
  unsigned short* xh = (unsigned short*)(ws + 65536);    // 4 MB fp16 (fragment layout)
  float* col_den = (float*)(ws + 65536 + 4194304);       // 32 KB
  float* col_num = col_den + B_ROWS;                     // 32 KB
  float* row_den = col_num + B_ROWS;                     // 32 KB
  float* row_num = row_den + B_ROWS;                     // 32 KB

  hipLaunchKernelGGL(prep_kernel, dim3(B_ROWS/4), dim3(256), 0, stream,
                     x, xh, sq, part_s, part_q, col_den, col_num,
                     row_den, row_num);
  hipLaunchKernelGGL(snn_main, dim3(NBLK), dim3(256), 0, stream,
                     xh, sq, y, T, part_s, part_q, row_den, row_num,
                     col_den, col_num);
  hipLaunchKernelGGL(final_kernel, dim3(1), dim3(1024), 0, stream,
                     row_den, row_num, col_den, col_num, (float*)d_out);
}